// Round 6
// baseline (37.774 us; speedup 1.0000x reference)
//
#include <hip/hip_runtime.h>

#define GRIDSZ 13
#define NANCH  5
#define NCHAN  25
#define BATCH  2048
#define NOBJ   32
#define PLANE  169                 // 13*13
#define ACH    (NCHAN * PLANE)     // 4225 floats per (batch,anchor)
#define WPB    4                   // waves (=batches) per block
#define NBLK   (BATCH / WPB)       // 512 blocks

// ANCHORS / 13, folded at compile time in IEEE f32 (matches JAX runtime division)
__constant__ float AW[NANCH] = {1.3221f / 13.0f, 3.19275f / 13.0f, 5.05587f / 13.0f,
                                9.47112f / 13.0f, 11.2364f / 13.0f};
__constant__ float AH[NANCH] = {1.73145f / 13.0f, 4.00944f / 13.0f, 8.09892f / 13.0f,
                                4.84053f / 13.0f, 10.0071f / 13.0f};

// One WAVE per batch image; 4 independent waves per block; ZERO __syncthreads.
// Per wave:
//   meta : lanes<32 load gt box/class, compute gx,gy (regs + small LDS)
//   D    : baseline 0.5*d4^2 over the batch's 5 ch-4 planes (coalesced, fused into load)
//   A    : 160 (gt,anchor) IoUs, 3 per lane, box via register shuffle -> iou LDS
//   B    : per-GT argmax (lane=gt) + winner resolution via 32 register shuffles
//   C1   : winner ch0-4 terms (lanes<32, scattered loads, L2-warm from A)
//   C2   : 640 (gt,class-ch) items, 10 per lane, scattered loads
// Wave writes one float4 partial {loss, obj, noobj, conf}.
__global__ void __launch_bounds__(256) main_kernel(const float* __restrict__ det,
                                                   const float* __restrict__ gt_boxes,
                                                   const int* __restrict__ gt_class,
                                                   float4* __restrict__ partials) {
    int wv   = threadIdx.x >> 6;
    int lane = threadIdx.x & 63;
    int batch = blockIdx.x * WPB + wv;

    __shared__ float iou_sm[WPB][NOBJ * NANCH];
    __shared__ int   gx_sm[WPB][NOBJ], gy_sm[WPB][NOBJ], cls_sm[WPB][NOBJ];
    __shared__ int   aidx_sm[WPB][NOBJ], win_sm[WPB][NOBJ];

    const float* detb = det + (size_t)batch * (NANCH * ACH);

    // ---- meta (lanes<32): box in registers, ints to per-wave LDS ----
    float4 g = make_float4(0.f, 0.f, 0.f, 0.f);
    int gx = 0, gy = 0;
    if (lane < NOBJ) {
        g = ((const float4*)gt_boxes)[batch * NOBJ + lane];
        gx = (int)floorf(g.x * 13.0f);
        gy = (int)floorf(g.y * 13.0f);
        gx_sm[wv][lane]  = gx;
        gy_sm[wv][lane]  = gy;
        cls_sm[wv][lane] = gt_class[batch * NOBJ + lane];
    }

    float loss = 0.f, objl = 0.f, noobjl = 0.f, confl = 0.f;

    // ---- D: baseline 0.5*d4^2, fused into the (coalesced) load loop ----
    {
        float s = 0.f;
        #pragma unroll
        for (int a = 0; a < NANCH; ++a) {
            const float* p = detb + (a * NCHAN + 4) * PLANE;
            for (int pos = lane; pos < PLANE; pos += 64) {
                float d = p[pos];
                s += d * d;
            }
        }
        loss   += 0.5f * s;
        noobjl += 0.5f * s;
    }

    // ---- A: IoU per (gt,anchor); 160 pairs, 3 per lane ----
    for (int pair = lane; pair < NOBJ * NANCH; pair += 64) {
        int gt = pair / NANCH;
        int a  = pair - gt * NANCH;
        float x = __shfl(g.x, gt);
        float y = __shfl(g.y, gt);
        float w = __shfl(g.z, gt);
        float h = __shfl(g.w, gt);
        int gxv = gx_sm[wv][gt], gyv = gy_sm[wv][gt];
        int pos = gyv * GRIDSZ + gxv;
        const float* p = detb + (size_t)a * ACH + pos;
        float px = p[0];
        float py = p[PLANE];
        float pw = p[2 * PLANE] * AW[a];
        float ph = p[3 * PLANE] * AH[a];
        float gx0 = x - w * 0.5f, gy0 = y - h * 0.5f;
        float gx1 = x + w * 0.5f, gy1 = y + h * 0.5f;
        float a1 = (gx1 - gx0 + 1.0f) * (gy1 - gy0 + 1.0f);
        float bx0 = (px + (float)gxv) / 13.0f - pw * 0.5f;
        float by0 = (py + (float)gyv) / 13.0f - ph * 0.5f;
        float bx1 = bx0 + pw, by1 = by0 + ph;
        float ix0 = fmaxf(gx0, bx0), iy0 = fmaxf(gy0, by0);
        float ix1 = fminf(gx1, bx1), iy1 = fminf(gy1, by1);
        float inter = (ix1 - ix0 + 1.0f) * (iy1 - iy0 + 1.0f);
        float a2 = (bx1 - bx0 + 1.0f) * (by1 - by0 + 1.0f);
        iou_sm[wv][pair] = inter / (a1 + a2 - inter);
    }

    // ---- B1: per-GT argmax (first-max, matches jnp.argmax); lane = gt ----
    int aidx = 0, flat = -1, win = 0;
    if (lane < NOBJ) {
        float best = -INFINITY;
        #pragma unroll
        for (int a = 0; a < NANCH; ++a) {
            float v = iou_sm[wv][lane * NANCH + a];
            if (v > best) { best = v; aidx = a; }
        }
        flat = (aidx * GRIDSZ + gy) * GRIDSZ + gx;   // batch-local slot
        win = 1;
    }
    // ---- B2: winner = no higher-index GT in batch with same slot (shuffles) ----
    #pragma unroll
    for (int m = 1; m < NOBJ; ++m) {
        int fm = __shfl(flat, m);
        if (lane < NOBJ && m > lane && fm == flat) win = 0;
    }
    if (lane < NOBJ) {
        aidx_sm[wv][lane] = aidx;
        win_sm[wv][lane]  = win;
    }

    // ---- C1: winner ch0-4 terms + baseline subtraction (lanes<32) ----
    if (lane < NOBJ && win) {
        int pos = gy * GRIDSZ + gx;
        const float* p = detb + (size_t)aidx * ACH + pos;
        float px = p[0];
        float py = p[PLANE];
        float pw = p[2 * PLANE] * AW[aidx];
        float ph = p[3 * PLANE] * AH[aidx];
        float d4 = p[4 * PLANE];
        float tx = g.x * 13.0f - (float)gx;
        float ty = g.y * 13.0f - (float)gy;
        float e, t, corr = 0.f;
        e = tx - px;   t = 5.0f * e * e; corr += t; objl += t;
        e = ty - py;   t = 5.0f * e * e; corr += t; objl += t;
        e = g.z - pw;  t = 5.0f * e * e; corr += t; objl += t;
        e = g.w - ph;  t = 5.0f * e * e; corr += t; objl += t;
        e = 1.0f - d4; t = e * e;        corr += t; objl += t;
        float sub = 0.5f * d4 * d4;   // baseline term this owned cell replaces
        loss   += corr - sub;
        noobjl -= sub;
    }

    // ---- C2: class-channel terms; 640 (gt,c) items, 10 per lane ----
    for (int item = lane; item < NOBJ * 20; item += 64) {
        int gt = item / 20;
        int c  = 5 + (item - gt * 20);
        if (win_sm[wv][gt]) {
            int av = aidx_sm[wv][gt];
            float d = detb[((size_t)av * NCHAN + c) * PLANE +
                           gy_sm[wv][gt] * GRIDSZ + gx_sm[wv][gt]];
            float gtv = (c - 5 == cls_sm[wv][gt]) ? 1.0f : 0.0f;
            float e = gtv - d;
            float t = e * e;
            loss  += t;
            confl += t;
        }
    }

    // ---- wave reduction -> one float4 partial per wave(=batch) ----
    #pragma unroll
    for (int off = 32; off > 0; off >>= 1) {
        loss   += __shfl_down(loss, off);
        objl   += __shfl_down(objl, off);
        noobjl += __shfl_down(noobjl, off);
        confl  += __shfl_down(confl, off);
    }
    if (lane == 0) {
        partials[batch] = make_float4(loss, objl, noobjl, confl);
    }
}

// Final: one block sums BATCH float4 partials and writes out[0..3].
__global__ void reduce_kernel(const float4* __restrict__ partials,
                              float* __restrict__ out) {
    float s0 = 0, s1 = 0, s2 = 0, s3 = 0;
    for (int i = threadIdx.x; i < BATCH; i += 256) {
        float4 v = partials[i];
        s0 += v.x; s1 += v.y; s2 += v.z; s3 += v.w;
    }
    #pragma unroll
    for (int off = 32; off > 0; off >>= 1) {
        s0 += __shfl_down(s0, off);
        s1 += __shfl_down(s1, off);
        s2 += __shfl_down(s2, off);
        s3 += __shfl_down(s3, off);
    }
    __shared__ float sm[4][4];
    int lane = threadIdx.x & 63;
    int wid  = threadIdx.x >> 6;
    if (lane == 0) {
        sm[wid][0] = s0; sm[wid][1] = s1; sm[wid][2] = s2; sm[wid][3] = s3;
    }
    __syncthreads();
    if (threadIdx.x == 0) {
        float a0 = 0, a1 = 0, a2 = 0, a3 = 0;
        #pragma unroll
        for (int i = 0; i < 4; ++i) {
            a0 += sm[i][0]; a1 += sm[i][1]; a2 += sm[i][2]; a3 += sm[i][3];
        }
        out[0] = a0; out[1] = a1; out[2] = a2; out[3] = a3;
    }
}

extern "C" void kernel_launch(void* const* d_in, const int* in_sizes, int n_in,
                              void* d_out, int out_size, void* d_ws, size_t ws_size,
                              hipStream_t stream) {
    const float* det = (const float*)d_in[0];
    const float* gtb = (const float*)d_in[1];
    const int*   gtc = (const int*)d_in[2];
    float* out = (float*)d_out;
    float4* partials = (float4*)d_ws;   // BATCH * 16 B = 32 KB

    main_kernel<<<NBLK, 256, 0, stream>>>(det, gtb, gtc, partials);
    reduce_kernel<<<1, 256, 0, stream>>>(partials, out);
}